// Round 10
// baseline (193.577 us; speedup 1.0000x reference)
//
#include <hip/hip_runtime.h>
#include <cstdint>

#define BATCHES 8
#define NPTS 2048
#define NF 512
#define KNN 32
#define WAVES 8   // 512-thread block = 8 waves
#define QPW 2     // queries per wave, SEQUENTIAL: select/gather phases of
                  // different waves interleave (wave-drift phase mixing)

// grid = 8 batches * 128 chunks = 1024 blocks = exactly 4 blocks/CU resident.
// batch = blockIdx & 7 (XCD L2 affinity for x[b] during gather).
// LDS = 32768 (pts4) + 4096 (ckey) + 1024 (sel) = 37888 B -> 4 blocks = 148 KB.
// (512,4): loose reg cap; tight caps scratch-spill db[32] (R4 evidence).

typedef float vfloat4 __attribute__((ext_vector_type(4)));  // native vec for nt-store

__global__ __launch_bounds__(512, 4)
void pointnetpp_knn_maxpool(const float* __restrict__ x,
                            const float* __restrict__ points,
                            float* __restrict__ out) {
    __shared__ __align__(16) float    pts4[NPTS * 4];    // [N][4]: one b128/candidate
    __shared__ __align__(16) uint64_t ckey[WAVES][64];   // candidate keys (fast path)
    __shared__ __align__(16) int      sel[WAVES][KNN];   // fallback emit only

    const int tid  = threadIdx.x;
    const int lane = tid & 63;
    const int w    = tid >> 6;

    const int b     = blockIdx.x & 7;
    const int chunk = blockIdx.x >> 3;

    // ---- stage points[b] into LDS as [N][4] (pad .w) ----
    {
        const float* src = points + (size_t)b * NPTS * 3;
        for (int p = tid; p < NPTS; p += 512) {
            float4* d = (float4*)&pts4[p * 4];
            *d = make_float4(src[p * 3 + 0], src[p * 3 + 1], src[p * 3 + 2], 0.f);
        }
    }
    __syncthreads();

    const uint64_t lmlt = (1ull << lane) - 1ull;
    const float*   xb   = x + (size_t)b * NPTS * NF;

    for (int q = 0; q < QPW; ++q) {
        const int i = chunk * (WAVES * QPW) + w * QPW + q;   // this wave's query

        const float4 qp = *(const float4*)&pts4[i * 4];

        // ---- squared distances (bit patterns; arithmetic identical R1..R9) ----
        uint32_t db[32];
        #pragma unroll
        for (int j = 0; j < 32; ++j) {
            const int n = lane + (j << 6);
            const float4 pp = *(const float4*)&pts4[n * 4];
            const float dx = qp.x - pp.x;
            const float dy = qp.y - pp.y;
            const float dz = qp.z - pp.z;
            db[j] = __float_as_uint(dx * dx + dy * dy + dz * dz);
        }

        auto countLE = [&](uint32_t t) {
            uint32_t c = 0;
            #pragma unroll
            for (int j = 0; j < 32; ++j)
                c += (uint32_t)__builtin_popcountll(__ballot(db[j] <= t));
            return c;
        };

        // ---- seed hi = wave_max(per-lane min): count(<=hi) >= 64 ----
        uint32_t lmin = db[0];
        #pragma unroll
        for (int j = 1; j < 32; ++j) lmin = min(lmin, db[j]);
        uint32_t hi = lmin;
        #pragma unroll
        for (int m = 1; m < 64; m <<= 1)
            hi = max(hi, (uint32_t)__shfl_xor((int)hi, m));
        uint32_t lo = 0u;   // count(<=0) = 1 (self) < KNN

        // ---- window search: any thr with 32 <= count(<=thr) <= 64 ----
        uint32_t thr = 0u, cthr = 0u;
        bool     have = false;
        {
            const uint32_t cs = countLE(hi);   // >= 64 by construction
            if (cs <= 64u) { thr = hi; cthr = cs; have = true; }
        }
        while (!have && hi - lo > 1u) {
            const uint32_t mid = lo + ((hi - lo) >> 1);
            const uint32_t c   = countLE(mid);
            if (c >= KNN && c <= 64u) { thr = mid; cthr = c; have = true; break; }
            if (c > 64u) hi = mid; else lo = mid;
        }

        int selv;   // per-lane: lanes 0..31 hold the 32 selected indices
        if (have) {
            // ---- compact <=64 candidates to LDS as keys (d2<<11 | idx) ----
            uint32_t base = 0;
            #pragma unroll
            for (int j = 0; j < 32; ++j) {
                const bool     p = db[j] <= thr;
                const uint64_t m = __ballot(p);
                if (p) {
                    const int slot = (int)base + (int)__popcll(m & lmlt);
                    ckey[w][slot] = (((uint64_t)db[j]) << 11) | (uint64_t)(lane + (j << 6));
                }
                base += (uint32_t)__builtin_popcountll(m);
            }
            uint64_t key = (lane < (int)cthr) ? ckey[w][lane] : ~0ull;

            // ---- wave bitonic sort64 ascending on (d2, idx) ----
            #pragma unroll
            for (int k = 2; k <= 64; k <<= 1) {
                #pragma unroll
                for (int j = k >> 1; j > 0; j >>= 1) {
                    const uint64_t other = __shfl_xor((unsigned long long)key, j);
                    const bool takeMin = (((lane & j) == 0) == ((lane & k) == 0));
                    const uint64_t mn = key < other ? key : other;
                    const uint64_t mx = key < other ? other : key;
                    key = takeMin ? mn : mx;
                }
            }
            selv = (int)(key & 0x7FFull);   // lanes 0..31: exact top-32
        } else {
            // ---- exact-tie fallback: T = hi; all <T, then ==T ascending-n ----
            const uint32_t T = hi;
            const int cnt_lt = (int)countLE(lo);   // count(<T)
            int base_lt = 0, base_eq = 0;
            #pragma unroll
            for (int j = 0; j < 32; ++j) {
                const bool lt = db[j] < T;
                const bool eq = db[j] == T;
                const uint64_t mlt = __ballot(lt);
                const uint64_t meq = __ballot(eq);
                int slot = -1;
                if (lt)      slot = base_lt + (int)__popcll(mlt & lmlt);
                else if (eq) slot = cnt_lt + base_eq + (int)__popcll(meq & lmlt);
                if (slot >= 0 && slot < KNN) sel[w][slot] = lane + (j << 6);
                base_lt += (int)__popcll(mlt);
                base_eq += (int)__popcll(meq);
            }
            selv = sel[w][lane & (KNN - 1)];
        }

        // ---- gather + max-pool: readlane broadcasts, float4 coalesced ----
        float4 a0 = make_float4(-INFINITY, -INFINITY, -INFINITY, -INFINITY);
        float4 a1 = a0;
        #pragma unroll 8
        for (int k = 0; k < KNN; ++k) {
            const int nb = __builtin_amdgcn_readlane(selv, k) & (NPTS - 1);
            const float4* row = (const float4*)(xb + (size_t)nb * NF);
            const float4 v0 = row[lane];
            const float4 v1 = row[lane + 64];
            a0.x = fmaxf(a0.x, v0.x);  a0.y = fmaxf(a0.y, v0.y);
            a0.z = fmaxf(a0.z, v0.z);  a0.w = fmaxf(a0.w, v0.w);
            a1.x = fmaxf(a1.x, v1.x);  a1.y = fmaxf(a1.y, v1.y);
            a1.z = fmaxf(a1.z, v1.z);  a1.w = fmaxf(a1.w, v1.w);
        }

        // ---- nontemporal stores: no L2 write-allocate, keep x[b] resident ----
        vfloat4* orow = (vfloat4*)(out + ((size_t)b * NPTS + i) * NF);
        const vfloat4 na0 = vfloat4{a0.x, a0.y, a0.z, a0.w};
        const vfloat4 na1 = vfloat4{a1.x, a1.y, a1.z, a1.w};
        __builtin_nontemporal_store(na0, &orow[lane]);
        __builtin_nontemporal_store(na1, &orow[lane + 64]);
    }
}

extern "C" void kernel_launch(void* const* d_in, const int* in_sizes, int n_in,
                              void* d_out, int out_size, void* d_ws, size_t ws_size,
                              hipStream_t stream) {
    const float* x      = (const float*)d_in[0];   // [8, 2048, 512] f32
    const float* points = (const float*)d_in[1];   // [8, 2048, 3]   f32
    float* out          = (float*)d_out;           // [8, 2048, 512] f32

    pointnetpp_knn_maxpool<<<dim3(BATCHES * (NPTS / (WAVES * QPW))),
                             dim3(512), 0, stream>>>(x, points, out);
}

// Round 11
// 134.587 us; speedup vs baseline: 1.4383x; 1.4383x over previous
//
#include <hip/hip_runtime.h>
#include <cstdint>

#define BATCHES 8
#define NPTS 2048
#define NF 512
#define KNN 32
#define WAVES 8   // 512-thread block = 8 waves
#define QPW 2     // queries per wave, STRAIGHT-LINE duplicated (no q-loop!):
                  // R10's q-loop made the allocator spill db[32] to scratch
                  // (VGPR 64 + 104MB spill writes). Manual duplication keeps
                  // R9's register shape (VGPR 32, AGPR offload, zero spill).

// grid = 8 batches * 128 chunks = 1024 blocks = exactly 4 blocks/CU resident.
// batch = blockIdx & 7 (XCD L2 affinity for x[b] during gather).
// LDS = 32768 (pts4) + 4096 (ckey) + 1024 (sel) = 37888 B -> 4 blocks = 148 KB.

typedef float vfloat4 __attribute__((ext_vector_type(4)));  // native vec for nt-store

__global__ __launch_bounds__(512, 4)
void pointnetpp_knn_maxpool(const float* __restrict__ x,
                            const float* __restrict__ points,
                            float* __restrict__ out) {
    __shared__ __align__(16) float    pts4[NPTS * 4];    // [N][4]: one b128/candidate
    __shared__ __align__(16) uint64_t ckey[WAVES][64];   // candidate keys (fast path)
    __shared__ __align__(16) int      sel[WAVES][KNN];   // fallback emit only

    const int tid  = threadIdx.x;
    const int lane = tid & 63;
    const int w    = tid >> 6;

    const int b     = blockIdx.x & 7;
    const int chunk = blockIdx.x >> 3;

    // ---- stage points[b] into LDS as [N][4] (pad .w) ----
    {
        const float* src = points + (size_t)b * NPTS * 3;
        for (int p = tid; p < NPTS; p += 512) {
            float4* d = (float4*)&pts4[p * 4];
            *d = make_float4(src[p * 3 + 0], src[p * 3 + 1], src[p * 3 + 2], 0.f);
        }
    }
    __syncthreads();

    const uint64_t lmlt = (1ull << lane) - 1ull;
    const float*   xb   = x + (size_t)b * NPTS * NF;

    // ---- full select+gather for one query (R9's verified body, verbatim) ----
    auto process = [&](const int i) __attribute__((always_inline)) -> void {
        const float4 qp = *(const float4*)&pts4[i * 4];

        // squared distances (bit patterns; arithmetic identical R1..R9)
        uint32_t db[32];
        #pragma unroll
        for (int j = 0; j < 32; ++j) {
            const int n = lane + (j << 6);
            const float4 pp = *(const float4*)&pts4[n * 4];
            const float dx = qp.x - pp.x;
            const float dy = qp.y - pp.y;
            const float dz = qp.z - pp.z;
            db[j] = __float_as_uint(dx * dx + dy * dy + dz * dz);
        }

        auto countLE = [&](uint32_t t) {
            uint32_t c = 0;
            #pragma unroll
            for (int j = 0; j < 32; ++j)
                c += (uint32_t)__builtin_popcountll(__ballot(db[j] <= t));
            return c;
        };

        // seed hi = wave_max(per-lane min): count(<=hi) >= 64
        uint32_t lmin = db[0];
        #pragma unroll
        for (int j = 1; j < 32; ++j) lmin = min(lmin, db[j]);
        uint32_t hi = lmin;
        #pragma unroll
        for (int m = 1; m < 64; m <<= 1)
            hi = max(hi, (uint32_t)__shfl_xor((int)hi, m));
        uint32_t lo = 0u;   // count(<=0) = 1 (self) < KNN

        // window search: any thr with 32 <= count(<=thr) <= 64
        uint32_t thr = 0u, cthr = 0u;
        bool     have = false;
        {
            const uint32_t cs = countLE(hi);   // >= 64 by construction
            if (cs <= 64u) { thr = hi; cthr = cs; have = true; }
        }
        while (!have && hi - lo > 1u) {
            const uint32_t mid = lo + ((hi - lo) >> 1);
            const uint32_t c   = countLE(mid);
            if (c >= KNN && c <= 64u) { thr = mid; cthr = c; have = true; break; }
            if (c > 64u) hi = mid; else lo = mid;
        }

        int selv;   // lanes 0..31 hold the 32 selected indices
        if (have) {
            // compact <=64 candidates to LDS as keys (d2<<11 | idx)
            uint32_t base = 0;
            #pragma unroll
            for (int j = 0; j < 32; ++j) {
                const bool     p = db[j] <= thr;
                const uint64_t m = __ballot(p);
                if (p) {
                    const int slot = (int)base + (int)__popcll(m & lmlt);
                    ckey[w][slot] = (((uint64_t)db[j]) << 11) | (uint64_t)(lane + (j << 6));
                }
                base += (uint32_t)__builtin_popcountll(m);
            }
            uint64_t key = (lane < (int)cthr) ? ckey[w][lane] : ~0ull;

            // wave bitonic sort64 ascending on (d2, idx)
            #pragma unroll
            for (int k = 2; k <= 64; k <<= 1) {
                #pragma unroll
                for (int j = k >> 1; j > 0; j >>= 1) {
                    const uint64_t other = __shfl_xor((unsigned long long)key, j);
                    const bool takeMin = (((lane & j) == 0) == ((lane & k) == 0));
                    const uint64_t mn = key < other ? key : other;
                    const uint64_t mx = key < other ? other : key;
                    key = takeMin ? mn : mx;
                }
            }
            selv = (int)(key & 0x7FFull);   // exact top-32 (ref tie order)
        } else {
            // exact-tie fallback: T = hi; all <T, then ==T ascending-n
            const uint32_t T = hi;
            const int cnt_lt = (int)countLE(lo);   // count(<T)
            int base_lt = 0, base_eq = 0;
            #pragma unroll
            for (int j = 0; j < 32; ++j) {
                const bool lt = db[j] < T;
                const bool eq = db[j] == T;
                const uint64_t mlt = __ballot(lt);
                const uint64_t meq = __ballot(eq);
                int slot = -1;
                if (lt)      slot = base_lt + (int)__popcll(mlt & lmlt);
                else if (eq) slot = cnt_lt + base_eq + (int)__popcll(meq & lmlt);
                if (slot >= 0 && slot < KNN) sel[w][slot] = lane + (j << 6);
                base_lt += (int)__popcll(mlt);
                base_eq += (int)__popcll(meq);
            }
            selv = sel[w][lane & (KNN - 1)];
        }

        // gather + max-pool: readlane broadcasts, float4 coalesced
        float4 a0 = make_float4(-INFINITY, -INFINITY, -INFINITY, -INFINITY);
        float4 a1 = a0;
        #pragma unroll 8
        for (int k = 0; k < KNN; ++k) {
            const int nb = __builtin_amdgcn_readlane(selv, k) & (NPTS - 1);
            const float4* row = (const float4*)(xb + (size_t)nb * NF);
            const float4 v0 = row[lane];
            const float4 v1 = row[lane + 64];
            a0.x = fmaxf(a0.x, v0.x);  a0.y = fmaxf(a0.y, v0.y);
            a0.z = fmaxf(a0.z, v0.z);  a0.w = fmaxf(a0.w, v0.w);
            a1.x = fmaxf(a1.x, v1.x);  a1.y = fmaxf(a1.y, v1.y);
            a1.z = fmaxf(a1.z, v1.z);  a1.w = fmaxf(a1.w, v1.w);
        }

        // nontemporal stores: no L2 write-allocate, keep x[b] resident
        vfloat4* orow = (vfloat4*)(out + ((size_t)b * NPTS + i) * NF);
        const vfloat4 na0 = vfloat4{a0.x, a0.y, a0.z, a0.w};
        const vfloat4 na1 = vfloat4{a1.x, a1.y, a1.z, a1.w};
        __builtin_nontemporal_store(na0, &orow[lane]);
        __builtin_nontemporal_store(na1, &orow[lane + 64]);
    };

    // straight-line: q0's registers are dead before q1's are live (no loop!)
    const int i0 = chunk * (WAVES * QPW) + w * QPW;
    process(i0);
    process(i0 + 1);
}

extern "C" void kernel_launch(void* const* d_in, const int* in_sizes, int n_in,
                              void* d_out, int out_size, void* d_ws, size_t ws_size,
                              hipStream_t stream) {
    const float* x      = (const float*)d_in[0];   // [8, 2048, 512] f32
    const float* points = (const float*)d_in[1];   // [8, 2048, 3]   f32
    float* out          = (float*)d_out;           // [8, 2048, 512] f32

    pointnetpp_knn_maxpool<<<dim3(BATCHES * (NPTS / (WAVES * QPW))),
                             dim3(512), 0, stream>>>(x, points, out);
}